// Round 5
// baseline (173.088 us; speedup 1.0000x reference)
//
#include <hip/hip_runtime.h>

// HybridQuantumNetQML — round 5: single fused kernel, double-buffered
// coalesced LDS staging.
//
// R4 evidence: k1 fell under the harness's 60us ws-poison fills; dur_us
// includes ~105us of harness resets, leaving ~60us addressable (k1+k2).
// Split-K overhead (9.2MB partial round-trip + 2nd launch) is pure waste now
// that loads are coalesced, and R3 proved occupancy isn't the limiter.
//
// Block = 256 thr = 4 waves = 64 samples (one per lane). ps-loop over the 7
// row strips INSIDE the kernel: LDS double buffer (2 x 64x128 floats, 64KB),
// register-prefetch strip ps+1 while computing ps, one barrier per strip.
// Staging: thread t, chunk k: f=k*256+t -> (s=f/28, c=f%28), float4 load
// x[sample(s)*784 + ps*112 + 4c] -> two XOR-swizzled float2 LDS writes
// (swizzle 2*(s&15), float2-preserving, closed within 32-float blocks).
// Compute: wave wv handles patch row 2ps+(wv>>1), cols 7*(wv&1)..+6; weight
// addresses wave-uniform -> s_load. acc[10]/lane across all strips; 4-wave
// LDS reduce (aliased over buf0) + wave-0 epilogue (qfc/sampler/log_softmax).
// 2 blocks/CU (LDS-capped): 8 waves/CU; ~57KB loads in flight per CU.

#define ROWF 128

__global__ __launch_bounds__(256, 2)
void qml_fused(const float* __restrict__ x,
               const float* __restrict__ wm,     // (787,10)
               const float* __restrict__ bias,   // (10,)
               const float* __restrict__ sw,     // (4,)
               float* __restrict__ out,          // (B,10)
               int B)
{
    __shared__ float lds[2][64 * ROWF];          // 64 KB

    const int t = threadIdx.x;
    const int lane = t & 63;
    const int wv = __builtin_amdgcn_readfirstlane((int)(t >> 6));
    const int g = blockIdx.x;

    int sample = g * 64 + lane;
    const bool s_ok = (sample < B);
    if (sample >= B) sample = B - 1;

    // ---- per-thread staging constants (computed once) ----
    const float* xb[7];      // global base per chunk (strip 0)
    int d0[7], d1[7];        // swizzled LDS float offsets
#pragma unroll
    for (int k = 0; k < 7; ++k) {
        const int f = k * 256 + t;
        const int s = f / 28;
        const int c = f - 28 * s;
        int sg = g * 64 + s; if (sg >= B) sg = B - 1;
        xb[k] = x + (size_t)sg * 784 + 4 * c;
        const int m2 = (s & 15) << 1;
        d0[k] = s * ROWF + ((4 * c) ^ m2);
        d1[k] = s * ROWF + ((4 * c + 2) ^ m2);
    }

    // ---- compute-side constants ----
    const int i_loc = wv >> 1;                    // patch row within strip
    const int jbase = 7 * (wv & 1);               // first patch col
    const int o_top = i_loc * 56 + 2 * jbase;     // local float offset
    const int m2c = (lane & 15) << 1;

    float acc[10];
#pragma unroll
    for (int c = 0; c < 10; ++c) acc[c] = 0.0f;
    float q0 = 0.f, q1 = 0.f, q2 = 0.f, q3 = 0.f;

    float4 pre[7];

    // prologue: load + write strip 0
#pragma unroll
    for (int k = 0; k < 7; ++k) pre[k] = *(const float4*)(xb[k]);
#pragma unroll
    for (int k = 0; k < 7; ++k) {
        *(float2*)(&lds[0][0] + d0[k]) = make_float2(pre[k].x, pre[k].y);
        *(float2*)(&lds[0][0] + d1[k]) = make_float2(pre[k].z, pre[k].w);
    }
    __syncthreads();

#pragma unroll
    for (int ps = 0; ps < 7; ++ps) {
        const int cur = ps & 1, nxt = cur ^ 1;

        if (ps < 6) {                              // prefetch strip ps+1
#pragma unroll
            for (int k = 0; k < 7; ++k)
                pre[k] = *(const float4*)(xb[k] + (ps + 1) * 112);
        }

        // ---- compute strip ps from lds[cur] ----
        const float* __restrict__ row = &lds[cur][0] + lane * ROWF;
        const int p0 = (2 * ps + i_loc) * 14 + jbase;

#pragma unroll
        for (int tt = 0; tt < 7; ++tt) {
            const int ot = o_top + 2 * tt;
            const float2 a = *(const float2*)(row + (ot ^ m2c));         // row 2i
            const float2 b = *(const float2*)(row + ((ot + 28) ^ m2c));  // row 2i+1

            const float c0 = __cosf(a.x);
            const float c1 = __cosf(a.y);
            const float c2 = __cosf(b.x);
            const float c3 = __cosf(b.y);
            const float v0 = c0, v1 = c0 * c1, v2 = c2, v3 = c2 * c3;

            if (ps == 0 && wv == 0 && tt == 0) { q0 = v0; q1 = v1; q2 = v2; q3 = v3; }

            const float* __restrict__ wr = wm + 40 * (p0 + tt);   // uniform -> s_load
#pragma unroll
            for (int c = 0; c < 10; ++c)
                acc[c] += v0 * wr[c] + v1 * wr[10 + c] + v2 * wr[20 + c] + v3 * wr[30 + c];
        }

        if (ps < 6) {                              // write strip ps+1 to other buffer
#pragma unroll
            for (int k = 0; k < 7; ++k) {
                *(float2*)(&lds[nxt][0] + d0[k]) = make_float2(pre[k].x, pre[k].y);
                *(float2*)(&lds[nxt][0] + d1[k]) = make_float2(pre[k].z, pre[k].w);
            }
        }
        __syncthreads();
    }

    // ---- 4-wave reduce (alias over lds[0]; all waves past final barrier) ----
    float* __restrict__ red = &lds[0][0];
    if (wv != 0) {
#pragma unroll
        for (int c = 0; c < 10; ++c) red[(wv - 1) * 704 + lane * 11 + c] = acc[c];
    }
    __syncthreads();

    if (wv == 0) {
#pragma unroll
        for (int c = 0; c < 10; ++c)
            acc[c] += red[lane * 11 + c] + red[704 + lane * 11 + c]
                    + red[1408 + lane * 11 + c];

        // qfc
        const float f0 = __cosf(q0), f1 = __cosf(q1);
        const float f2 = __cosf(q2), f3 = __cosf(q3);
        const float qfc = (f0 + f0 * f1 + f2 + f2 * f3) * 0.25f;

        // sampler softmax
        const float t0 = q0 + sw[0] + sw[2];
        const float t1 = q1 + sw[1] + sw[3];
        const float z0 = __cosf(t0);
        const float z1 = z0 * __cosf(t1);
        const float e0 = __expf(z0);
        const float e1 = __expf(z1);
        const float inv = 1.0f / (e0 + e1);
        const float s0 = e0 * inv, s1 = e1 * inv;

        // tail rows + bias
        const float* __restrict__ wt = wm + 7840;
#pragma unroll
        for (int c = 0; c < 10; ++c)
            acc[c] += qfc * wt[c] + s0 * wt[10 + c] + s1 * wt[20 + c] + bias[c];

        // log_softmax
        float m = acc[0];
#pragma unroll
        for (int c = 1; c < 10; ++c) m = fmaxf(m, acc[c]);
        float ssum = 0.0f;
#pragma unroll
        for (int c = 0; c < 10; ++c) ssum += __expf(acc[c] - m);
        const float lse = __logf(ssum) + m;

        if (s_ok) {
            float* __restrict__ orow = out + (size_t)sample * 10;
#pragma unroll
            for (int c = 0; c < 10; ++c) orow[c] = acc[c] - lse;
        }
    }
}

extern "C" void kernel_launch(void* const* d_in, const int* in_sizes, int n_in,
                              void* d_out, int out_size, void* d_ws, size_t ws_size,
                              hipStream_t stream) {
    const float* x    = (const float*)d_in[0];   // (B,1,28,28) f32
    const float* w    = (const float*)d_in[1];   // (787,10)    f32
    const float* bias = (const float*)d_in[2];   // (10,)       f32
    const float* sw   = (const float*)d_in[3];   // (4,)        f32
    float* out = (float*)d_out;                  // (B,10)      f32

    const int B = in_sizes[0] / 784;
    const int nblk = (B + 63) / 64;
    qml_fused<<<nblk, 256, 0, stream>>>(x, w, bias, sw, out, B);
}

// Round 7
// 162.229 us; speedup vs baseline: 1.0669x; 1.0669x over previous
//
#include <hip/hip_runtime.h>

// HybridQuantumNetQML — round 7: round-6 MFMA GEMM + epilogue fix.
//
// R6 bug: epilogue used `if (t < 640)` from the 640-thread k2 of R4, but the
// fused block has 256 threads -> samples 26..63/block never written (absmax
// 114 = |log_softmax| of a zeroed row). Fix: grid-stride epilogue loops
// (e = t; e < 640; e += 256). All fragment layouts / LDS overlays audited
// and unchanged.
//
// Structure (unchanged from R6):
// C[64x10] = A(cos features, bf16) x B(W, bf16) via mfma_f32_16x16x32_bf16.
// K permuted strip-wise: strip s = 2 patch rows = 112 k, padded to 128
// (zero slots) -> 4 K-steps of 32; A and B share the permutation so the
// GEMM is exact. B-frags built once from LDS-staged W (28KB). A-frags
// built by staging threads directly in fragment layout (two float4 x-loads
// + 8 cos + bf16 pack per 16B chunk), XOR-swizzled, double-buffered per
// strip with register prefetch. No scalar loads in the hot loop.
// LDS: B 28672 + A-dbuf 32768 (overlaid by rawW, then logits) + qf 1024
//      = 62464 B -> 2 blocks/CU.

typedef __attribute__((ext_vector_type(8))) short short8;
typedef __attribute__((ext_vector_type(4))) float floatx4;

__device__ __forceinline__ unsigned short f2bf(float f) {
    unsigned u = __float_as_uint(f);
    return (unsigned short)((u + 0x7FFFu + ((u >> 16) & 1u)) >> 16);
}

#define A_OFF  28672
#define QF_OFF 61440

__global__ __launch_bounds__(256, 2)
void qml_mfma(const float* __restrict__ x,
              const float* __restrict__ wm,     // (787,10) f32
              const float* __restrict__ bias,   // (10,)
              const float* __restrict__ sw,     // (4,)
              float* __restrict__ out,          // (B,10)
              int B)
{
    __shared__ __align__(16) char smem[62464];
    float* rawW = (float*)(smem + A_OFF);      // phase 0/1 only
    float* qf   = (float*)(smem + QF_OFF);     // 64 x 4 f32
    float* lg   = (float*)(smem + A_OFF);      // epilogue logits 64 x 11

    const int t = threadIdx.x;
    const int lane = t & 63;
    const int wv = __builtin_amdgcn_readfirstlane((int)(t >> 6));
    const int g = blockIdx.x;

    // ---- phase 0: stage raw W -> LDS (coalesced) ----
    for (int i = t; i < 7870; i += 256) rawW[i] = wm[i];
    __syncthreads();

    // ---- phase 1: build B-fragments (28 K-steps x 64 lanes) ----
#pragma unroll
    for (int c = 0; c < 7; ++c) {
        const int CH = c * 256 + t;
        const int T = CH >> 6, L = CH & 63;
        const int n = L & 15, kq = L >> 4;
        short8 v;
#pragma unroll
        for (int j = 0; j < 8; ++j) {
            const int kh = 32 * T + kq * 8 + j;      // permuted k
            const int sg = kh >> 7, kl = kh & 127;   // strip, local slot
            float w = 0.0f;
            if (kl < 112 && n < 10) w = rawW[(112 * sg + kl) * 10 + n];
            v[j] = (short)f2bf(w);
        }
        *(short8*)(smem + CH * 16) = v;
    }
    __syncthreads();   // rawW dead after this

    // ---- staging constants: 4 A-chunks per thread per strip ----
    int st_pr[4], st_s[4], st_unit[4];
    const float* st_px[4];
#pragma unroll
    for (int c4 = 0; c4 < 4; ++c4) {
        const int G = c4 * 256 + t;
        const int s = G >> 4, pr = G & 15;           // sample, patch-pair
        st_s[c4] = s; st_pr[c4] = pr;
        st_unit[c4] = s * 16 + (pr ^ (s & 15));      // swizzled 16B-unit
        int sglob = g * 64 + s; if (sglob >= B) sglob = B - 1;
        const int r = (pr >= 7) ? 1 : 0;             // patch row within strip
        const int cq = (pr >= 7) ? (pr - 7) : pr;    // pair col (0..6)
        st_px[c4] = x + (size_t)sglob * 784 + r * 56 + 4 * cq;
    }

    floatx4 tp[4], bt[4];

    // compute-side constants
    const int sA = wv * 16 + (lane & 15);
    const int swzA = sA & 15;
    const int prq = lane >> 4;

    floatx4 acc = {0.f, 0.f, 0.f, 0.f};

    // ---- prologue: load + process strip 0 into buf 0 ----
#pragma unroll
    for (int c4 = 0; c4 < 4; ++c4)
        if (st_pr[c4] < 14) {
            tp[c4] = *(const floatx4*)(st_px[c4]);
            bt[c4] = *(const floatx4*)(st_px[c4] + 28);
        }
#pragma unroll
    for (int c4 = 0; c4 < 4; ++c4) {
        float f0 = 0.f, f1 = 0.f, f2 = 0.f, f3 = 0.f;
        float f4 = 0.f, f5 = 0.f, f6 = 0.f, f7 = 0.f;
        if (st_pr[c4] < 14) {
            const float c0 = __cosf(tp[c4].x), c1 = __cosf(tp[c4].y);
            const float c2 = __cosf(bt[c4].x), c3 = __cosf(bt[c4].y);
            f0 = c0; f1 = c0 * c1; f2 = c2; f3 = c2 * c3;
            const float c4_ = __cosf(tp[c4].z), c5 = __cosf(tp[c4].w);
            const float c6 = __cosf(bt[c4].z), c7 = __cosf(bt[c4].w);
            f4 = c4_; f5 = c4_ * c5; f6 = c6; f7 = c6 * c7;
            if (st_pr[c4] == 0) {                     // strip 0: qfeat[0:4]
                float* qd = qf + st_s[c4] * 4;
                qd[0] = f0; qd[1] = f1; qd[2] = f2; qd[3] = f3;
            }
        }
        short8 v;
        v[0] = (short)f2bf(f0); v[1] = (short)f2bf(f1);
        v[2] = (short)f2bf(f2); v[3] = (short)f2bf(f3);
        v[4] = (short)f2bf(f4); v[5] = (short)f2bf(f5);
        v[6] = (short)f2bf(f6); v[7] = (short)f2bf(f7);
        *(short8*)(smem + A_OFF + st_unit[c4] * 16) = v;
    }
    __syncthreads();

    // ---- strip loop ----
#pragma unroll
    for (int sg = 0; sg < 7; ++sg) {
        const int buf = sg & 1;

        if (sg < 6) {                                 // prefetch strip sg+1
#pragma unroll
            for (int c4 = 0; c4 < 4; ++c4)
                if (st_pr[c4] < 14) {
                    tp[c4] = *(const floatx4*)(st_px[c4] + (sg + 1) * 112);
                    bt[c4] = *(const floatx4*)(st_px[c4] + (sg + 1) * 112 + 28);
                }
        }

        // MFMA over this strip's 4 K-steps
#pragma unroll
        for (int tl = 0; tl < 4; ++tl) {
            const int pr = 4 * tl + prq;
            const short8 a = *(const short8*)(smem + A_OFF + buf * 16384
                                              + (sA * 16 + (pr ^ swzA)) * 16);
            const short8 b = *(const short8*)(smem + ((4 * sg + tl) * 64 + lane) * 16);
            acc = __builtin_amdgcn_mfma_f32_16x16x32_bf16(a, b, acc, 0, 0, 0);
        }

        if (sg < 6) {                                 // process into other buffer
#pragma unroll
            for (int c4 = 0; c4 < 4; ++c4) {
                float f0 = 0.f, f1 = 0.f, f2 = 0.f, f3 = 0.f;
                float f4 = 0.f, f5 = 0.f, f6 = 0.f, f7 = 0.f;
                if (st_pr[c4] < 14) {
                    const float c0 = __cosf(tp[c4].x), c1 = __cosf(tp[c4].y);
                    const float c2 = __cosf(bt[c4].x), c3 = __cosf(bt[c4].y);
                    f0 = c0; f1 = c0 * c1; f2 = c2; f3 = c2 * c3;
                    const float c4_ = __cosf(tp[c4].z), c5 = __cosf(tp[c4].w);
                    const float c6 = __cosf(bt[c4].z), c7 = __cosf(bt[c4].w);
                    f4 = c4_; f5 = c4_ * c5; f6 = c6; f7 = c6 * c7;
                }
                short8 v;
                v[0] = (short)f2bf(f0); v[1] = (short)f2bf(f1);
                v[2] = (short)f2bf(f2); v[3] = (short)f2bf(f3);
                v[4] = (short)f2bf(f4); v[5] = (short)f2bf(f5);
                v[6] = (short)f2bf(f6); v[7] = (short)f2bf(f7);
                *(short8*)(smem + A_OFF + (buf ^ 1) * 16384 + st_unit[c4] * 16) = v;
            }
        }
        __syncthreads();
    }

    // ---- epilogue: C -> lg (reuses A region; all MFMA reads done) ----
    {
        const int n = lane & 15;
        const int rbase = wv * 16 + (lane >> 4) * 4;   // C row = (lane>>4)*4+reg
        if (n < 10) {
#pragma unroll
            for (int r = 0; r < 4; ++r) lg[(rbase + r) * 11 + n] = acc[r];
        }
    }
    __syncthreads();

    // pass 1: add qfc/sampler/tail/bias (grid-stride over 640 (s,c) pairs)
#pragma unroll
    for (int e = t; e < 640; e += 256) {
        const int s2 = e / 10, c2 = e - 10 * s2;
        float logit = lg[s2 * 11 + c2];
        const float q0 = qf[s2 * 4 + 0], q1 = qf[s2 * 4 + 1];
        const float q2 = qf[s2 * 4 + 2], q3 = qf[s2 * 4 + 3];

        const float f0 = __cosf(q0), f1 = __cosf(q1);
        const float f2 = __cosf(q2), f3 = __cosf(q3);
        const float qfc = (f0 + f0 * f1 + f2 + f2 * f3) * 0.25f;

        const float t0 = q0 + sw[0] + sw[2];
        const float t1 = q1 + sw[1] + sw[3];
        const float z0 = __cosf(t0);
        const float z1 = z0 * __cosf(t1);
        const float e0 = __expf(z0), e1 = __expf(z1);
        const float inv = 1.0f / (e0 + e1);

        const float* __restrict__ wt = wm + 7840;      // rows 784..786
        logit += bias[c2] + qfc * wt[c2] + (e0 * inv) * wt[10 + c2]
                          + (e1 * inv) * wt[20 + c2];
        lg[s2 * 11 + c2] = logit;
    }
    __syncthreads();

    // pass 2: log_softmax + coalesced store
#pragma unroll
    for (int e = t; e < 640; e += 256) {
        const int s2 = e / 10, c2 = e - 10 * s2;
        float m = -3.4e38f;
#pragma unroll
        for (int k = 0; k < 10; ++k) m = fmaxf(m, lg[s2 * 11 + k]);
        float ss = 0.0f;
#pragma unroll
        for (int k = 0; k < 10; ++k) ss += __expf(lg[s2 * 11 + k] - m);
        const float lse = __logf(ss) + m;
        if (g * 64 + s2 < B)
            out[(size_t)g * 640 + e] = lg[s2 * 11 + c2] - lse;
    }
}

extern "C" void kernel_launch(void* const* d_in, const int* in_sizes, int n_in,
                              void* d_out, int out_size, void* d_ws, size_t ws_size,
                              hipStream_t stream) {
    const float* x    = (const float*)d_in[0];   // (B,1,28,28) f32
    const float* w    = (const float*)d_in[1];   // (787,10)    f32
    const float* bias = (const float*)d_in[2];   // (10,)       f32
    const float* sw   = (const float*)d_in[3];   // (4,)        f32
    float* out = (float*)d_out;                  // (B,10)      f32

    const int B = in_sizes[0] / 784;
    const int nblk = (B + 63) / 64;
    qml_mfma<<<nblk, 256, 0, stream>>>(x, w, bias, sw, out, B);
}

// Round 8
// 161.267 us; speedup vs baseline: 1.0733x; 1.0060x over previous
//
#include <hip/hip_runtime.h>

// HybridQuantumNetQML — round 8: barrier-free K-loop, wave-private A loads.
//
// R7 evidence: MFMA didn't move the needle (52us vs R5's 62) -> the shared
// invariant across ALL rounds is the staged-load/barrier cadence: tiny load
// batches + __syncthreads each strip = one full memory latency per strip,
// ~2 TB/s effective. Fix: exploit that the 16x16x32 A-fragment slice of
// lane (m=lane&15, q=lane>>4) is exactly one patch-pair = two float4 of x.
// Each wave owns 16 samples and loads its A-fragments DIRECTLY from global,
// cos+bf16-pack in registers, MFMA with B from LDS (ds_read_b128).
// No __syncthreads anywhere in the K-loop; prefetch depth 2 strips
// (~16 outstanding float4/lane -> ~64KB/CU in flight, saturates CU's HBM
// share). B-fragments + K-permutation + epilogue reused verbatim from the
// correctness-verified R7 kernel.
//
// K permutation (same as R7): strip sg = 2 image-row-pairs = 14 patch-pairs
// = 112 k, padded to 128 -> 4 K-steps of 32. Pair pr(T,q) = 4T+q, row
// r = pr>=7, col cq = pr-7r; k = 32T+8q+j, feature j of the pair =
// [p0: c0, c0c1, c2, c2c3 | p1: c4, c4c5, c6, c6c7] from top/bot float4.
// B[k][n]: lane (n=L&15, kq=L>>4), element j at k=32T+8kq+j (phase 1).
//
// LDS: B 28672 + scratch 31488 (rawW, then logits 64x11) + qf 1024 = 61184
//      -> 2 blocks/CU = 8 waves/CU (all the work there is: 2048 waves).

typedef __attribute__((ext_vector_type(8))) short short8;
typedef __attribute__((ext_vector_type(4))) float floatx4;

__device__ __forceinline__ unsigned short f2bf(float f) {
    unsigned u = __float_as_uint(f);
    return (unsigned short)((u + 0x7FFFu + ((u >> 16) & 1u)) >> 16);
}

#define SCR_OFF 28672
#define QF_OFF  60160

__global__ __launch_bounds__(256, 2)
void qml_mfma(const float* __restrict__ x,
              const float* __restrict__ wm,     // (787,10) f32
              const float* __restrict__ bias,   // (10,)
              const float* __restrict__ sw,     // (4,)
              float* __restrict__ out,          // (B,10)
              int B)
{
    __shared__ __align__(16) char smem[61184];
    float* rawW = (float*)(smem + SCR_OFF);    // phases 0/1 only
    float* lg   = (float*)(smem + SCR_OFF);    // epilogue logits 64 x 11
    float* qf   = (float*)(smem + QF_OFF);     // 64 x 4 f32

    const int t = threadIdx.x;
    const int lane = t & 63;
    const int wv = __builtin_amdgcn_readfirstlane((int)(t >> 6));
    const int g = blockIdx.x;

    // ---- phase 0: stage raw W -> LDS (coalesced) ----
    for (int i = t; i < 7870; i += 256) rawW[i] = wm[i];
    __syncthreads();

    // ---- phase 1: build B-fragments (28 K-steps x 64 lanes) [R7 verbatim] ----
#pragma unroll
    for (int c = 0; c < 7; ++c) {
        const int CH = c * 256 + t;
        const int T = CH >> 6, L = CH & 63;
        const int n = L & 15, kq = L >> 4;
        short8 v;
#pragma unroll
        for (int j = 0; j < 8; ++j) {
            const int kh = 32 * T + kq * 8 + j;      // permuted k
            const int sg = kh >> 7, kl = kh & 127;   // strip, local slot
            float w = 0.0f;
            if (kl < 112 && n < 10) w = rawW[(112 * sg + kl) * 10 + n];
            v[j] = (short)f2bf(w);
        }
        *(short8*)(smem + CH * 16) = v;
    }
    __syncthreads();   // rawW dead; ONLY barrier before the epilogue

    // ---- wave-private A-path setup ----
    const int m = lane & 15;                   // sample within wave
    const int q = lane >> 4;                   // k-quad
    int sample = g * 64 + wv * 16 + m;
    const bool s_ok = (sample < B);
    if (sample >= B) sample = B - 1;
    const float* __restrict__ xs = x + (size_t)sample * 784;

    int offT[4], validT[4];
#pragma unroll
    for (int T = 0; T < 4; ++T) {
        const int pr = 4 * T + q;              // patch-pair within strip
        validT[T] = (pr < 14);
        const int r = (pr >= 7) ? 1 : 0;
        const int cq = (pr >= 7) ? (pr - 7) : pr;
        offT[T] = validT[T] ? (r * 56 + 4 * cq) : 0;   // safe addr if invalid
    }

    floatx4 tp[3][4], bt[3][4];                // 2-deep strip pipeline (mod 3)

#define LOADSTRIP(slot, sg_)                                            \
    {                                                                   \
        _Pragma("unroll")                                               \
        for (int T = 0; T < 4; ++T) {                                   \
            tp[slot][T] = *(const floatx4*)(xs + (sg_) * 112 + offT[T]);        \
            bt[slot][T] = *(const floatx4*)(xs + (sg_) * 112 + offT[T] + 28);   \
        }                                                               \
    }

    floatx4 acc = {0.f, 0.f, 0.f, 0.f};

    LOADSTRIP(0, 0)
    LOADSTRIP(1, 1)

#pragma unroll
    for (int sg = 0; sg < 7; ++sg) {
        const int slot = sg % 3;
        if (sg < 5) {
            const int ns = (sg + 2) % 3;
            LOADSTRIP(ns, sg + 2)
        }

#pragma unroll
        for (int T = 0; T < 4; ++T) {
            const floatx4 P = tp[slot][T];
            const floatx4 Q = bt[slot][T];
            const float c0 = __cosf(P.x), c1 = __cosf(P.y);
            const float c2 = __cosf(Q.x), c3 = __cosf(Q.y);
            const float c4 = __cosf(P.z), c5 = __cosf(P.w);
            const float c6 = __cosf(Q.z), c7 = __cosf(Q.w);
            const float f0 = c0, f1 = c0 * c1, f2 = c2, f3 = c2 * c3;
            const float f4 = c4, f5 = c4 * c5, f6 = c6, f7 = c6 * c7;

            if (sg == 0 && T == 0 && q == 0) {         // pair 0 = patches 0,1
                float* qd = qf + (wv * 16 + m) * 4;
                qd[0] = f0; qd[1] = f1; qd[2] = f2; qd[3] = f3;
            }

            short8 a;
            a[0] = (short)f2bf(f0); a[1] = (short)f2bf(f1);
            a[2] = (short)f2bf(f2); a[3] = (short)f2bf(f3);
            a[4] = (short)f2bf(f4); a[5] = (short)f2bf(f5);
            a[6] = (short)f2bf(f6); a[7] = (short)f2bf(f7);
            if (!validT[T]) {
                a = (short8){0, 0, 0, 0, 0, 0, 0, 0};  // padded k-slots
            }

            const short8 b8 = *(const short8*)(smem + ((4 * sg + T) * 64 + lane) * 16);
            acc = __builtin_amdgcn_mfma_f32_16x16x32_bf16(a, b8, acc, 0, 0, 0);
        }
    }

    // ---- epilogue (R7 structure; lg overlays rawW region) ----
    {
        const int n = lane & 15;
        const int rbase = wv * 16 + (lane >> 4) * 4;   // C row = (lane>>4)*4+reg
        if (n < 10) {
#pragma unroll
            for (int r = 0; r < 4; ++r) lg[(rbase + r) * 11 + n] = acc[r];
        }
    }
    __syncthreads();

    // pass 1: add qfc/sampler/tail/bias (grid-stride over 640 (s,c) pairs)
#pragma unroll
    for (int e = t; e < 640; e += 256) {
        const int s2 = e / 10, c2 = e - 10 * s2;
        float logit = lg[s2 * 11 + c2];
        const float q0 = qf[s2 * 4 + 0], q1 = qf[s2 * 4 + 1];
        const float q2 = qf[s2 * 4 + 2], q3 = qf[s2 * 4 + 3];

        const float f0 = __cosf(q0), f1 = __cosf(q1);
        const float f2 = __cosf(q2), f3 = __cosf(q3);
        const float qfc = (f0 + f0 * f1 + f2 + f2 * f3) * 0.25f;

        const float t0 = q0 + sw[0] + sw[2];
        const float t1 = q1 + sw[1] + sw[3];
        const float z0 = __cosf(t0);
        const float z1 = z0 * __cosf(t1);
        const float e0 = __expf(z0), e1 = __expf(z1);
        const float inv = 1.0f / (e0 + e1);

        const float* __restrict__ wt = wm + 7840;      // rows 784..786
        logit += bias[c2] + qfc * wt[c2] + (e0 * inv) * wt[10 + c2]
                          + (e1 * inv) * wt[20 + c2];
        lg[s2 * 11 + c2] = logit;
    }
    __syncthreads();

    // pass 2: log_softmax + coalesced store
#pragma unroll
    for (int e = t; e < 640; e += 256) {
        const int s2 = e / 10, c2 = e - 10 * s2;
        float mx = -3.4e38f;
#pragma unroll
        for (int k = 0; k < 10; ++k) mx = fmaxf(mx, lg[s2 * 11 + k]);
        float ss = 0.0f;
#pragma unroll
        for (int k = 0; k < 10; ++k) ss += __expf(lg[s2 * 11 + k] - mx);
        const float lse = __logf(ss) + mx;
        if (g * 64 + s2 < B)
            out[(size_t)g * 640 + e] = lg[s2 * 11 + c2] - lse;
    }
}

extern "C" void kernel_launch(void* const* d_in, const int* in_sizes, int n_in,
                              void* d_out, int out_size, void* d_ws, size_t ws_size,
                              hipStream_t stream) {
    const float* x    = (const float*)d_in[0];   // (B,1,28,28) f32
    const float* w    = (const float*)d_in[1];   // (787,10)    f32
    const float* bias = (const float*)d_in[2];   // (10,)       f32
    const float* sw   = (const float*)d_in[3];   // (4,)        f32
    float* out = (float*)d_out;                  // (B,10)      f32

    const int B = in_sizes[0] / 784;
    const int nblk = (B + 63) / 64;
    qml_mfma<<<nblk, 256, 0, stream>>>(x, w, bias, sw, out, B);
}